// Round 2
// baseline (688.864 us; speedup 1.0000x reference)
//
#include <hip/hip_runtime.h>

// Problem constants (B,C,T,V)=(32,128,64,25), N_STEP=8, DILATION=1
#define CC     128
#define TT     64
#define VV     25
#define BB     32
#define PP     (TT * VV)          // 1600 positions per (b, c)
#define CHUNK  (BB * CC * PP)     // 6,553,600 elems per output chunk
#define NSTEP  8
#define PTILE  32                 // positions per block tile
#define NPT    (PP / PTILE)       // 50 tiles per batch

typedef __attribute__((ext_vector_type(8))) __bf16 bf16x8;   // MFMA A/B frag (4 VGPR)
typedef __attribute__((ext_vector_type(4))) float  f32x4;    // MFMA C/D frag

__device__ __forceinline__ float fast_tanh(float x) {
    float e = __expf(2.0f * x);
    return 1.0f - 2.0f * __builtin_amdgcn_rcpf(e + 1.0f);
}

// Split fp32 into truncated-bf16 hi + truncated-bf16 lo (residual <= 2^-16 rel).
__device__ __forceinline__ void bf16_split(float y, unsigned short& h, unsigned short& lo) {
    unsigned int bits = __float_as_uint(y);
    h = (unsigned short)(bits >> 16);
    float r = y - __uint_as_float(bits & 0xffff0000u);
    lo = (unsigned short)(__float_as_uint(r) >> 16);
}

// Byte offset of (p, c) in an [PTILE][CC] ushort LDS tile, XOR-swizzled.
// (p&7)<<4 spreads 8 rows over 8 x 16B slots; (p&8)<<3 splits rows p / p+8
// so the scalar b16 publish writes are 2-way (free) instead of 4-way.
__device__ __forceinline__ int xb_off(int p, int c) {
    return (p * 256 + c * 2) ^ ((p & 7) << 4) ^ ((p & 8) << 3);
}

// LDS-only barrier: waits own DS ops, does NOT drain vmcnt (global stores keep
// flowing across steps). sched_barrier fences per guide rule #18.
__device__ __forceinline__ void lds_barrier() {
    asm volatile("s_waitcnt lgkmcnt(0)" ::: "memory");
    __builtin_amdgcn_sched_barrier(0);
    __builtin_amdgcn_s_barrier();
    __builtin_amdgcn_sched_barrier(0);
}

// ---- tiny one-time kernel: W -> bf16 hi/lo pair in workspace ----------------
__global__ void wsplit(const float* __restrict__ W,
                       unsigned short* __restrict__ Wh, unsigned short* __restrict__ Wl) {
    int idx = blockIdx.x * 256 + threadIdx.x;       // 16384 total
    if (idx < CC * CC) {
        unsigned short h, lo;
        bf16_split(W[idx], h, lo);
        Wh[idx] = h;
        Wl[idx] = lo;
    }
}

// ---- fused 8-step Euler kernel, split-bf16 MFMA, swapped operands ------------
// D = X^T * W^T : row = position, col = channel. Each lane holds 4 CONSECUTIVE
// positions per (ptile,dtile) -> float4 global stores. State double-buffered in
// LDS as bf16 hi/lo [p][c]; one LDS-only barrier per step (no vmcnt drain).
__global__ __launch_bounds__(256, 4) void euler_fused(
    const float* __restrict__ z, const unsigned short* __restrict__ Wh,
    const unsigned short* __restrict__ Wl, const float* __restrict__ bias,
    float* __restrict__ out)
{
    __shared__ unsigned short XH[2][PTILE * CC];    // 2 x 8 KB bf16-hi state
    __shared__ unsigned short XL[2][PTILE * CC];    // 2 x 8 KB bf16-lo state

    const int b   = blockIdx.y;
    const int p0  = blockIdx.x * PTILE;
    const int tid = threadIdx.x;
    const int w   = tid >> 6;          // wave 0..3 -> d-tiles {2w, 2w+1}
    const int lr  = tid & 15;          // lane&15: B-col (=d) / A-row (=p) / D-col
    const int lh  = (tid >> 4) & 3;    // lane>>4: k-group / D-row-group

    // ---- W fragments (B operand: B[k=c][col=d] = W[d][c]), hi+lo, registers ----
    bf16x8 wh[2][4], wl[2][4];
    #pragma unroll
    for (int dt = 0; dt < 2; ++dt) {
        const int d = (2 * w + dt) * 16 + lr;
        #pragma unroll
        for (int ks = 0; ks < 4; ++ks) {
            const int cb = ks * 32 + lh * 8;
            wh[dt][ks] = *(const bf16x8*)(Wh + d * CC + cb);
            wl[dt][ks] = *(const bf16x8*)(Wl + d * CC + cb);
        }
    }

    // bias is per-column now: one scalar per d-tile
    float bv[2];
    #pragma unroll
    for (int dt = 0; dt < 2; ++dt) bv[dt] = bias[(2 * w + dt) * 16 + lr];

    // ---- prologue: cooperative z-tile load -> chunk-0 outputs + XH/XL[0] ----
    const float* zb = z + (size_t)b * CC * PP + p0;
    #pragma unroll
    for (int it = 0; it < 4; ++it) {
        int slot = it * 256 + tid;                  // 1024 float4 slots
        int c  = slot >> 3;                         // 8 float4 per 32-pos row
        int po = (slot & 7) * 4;
        float4 v = *(const float4*)(zb + (size_t)c * PP + po);
        size_t o = (size_t)(b * CC + c) * PP + p0 + po;
        *(float4*)(out + o)                     = v;   // z_shift chunk 0 (= z)
        *(float4*)(out + (size_t)9 * CHUNK + o) = v;   // z_cls   chunk 0 (= z)
        float vv[4] = {v.x, v.y, v.z, v.w};
        #pragma unroll
        for (int e = 0; e < 4; ++e) {
            unsigned short h, lo;
            bf16_split(vv[e], h, lo);
            int off = xb_off(po + e, c);
            *(unsigned short*)((char*)XH[0] + off) = h;
            *(unsigned short*)((char*)XL[0] + off) = lo;
        }
    }

    // ---- fp32 state in registers at this lane's D-layout slots:
    // st[pt][dt][j] = X[d = (2w+dt)*16+lr][p = p0 + pt*16 + lh*4 + j]  (float4 loads)
    f32x4 st[2][2];
    #pragma unroll
    for (int pt = 0; pt < 2; ++pt)
        #pragma unroll
        for (int dt = 0; dt < 2; ++dt) {
            const int d = (2 * w + dt) * 16 + lr;
            st[pt][dt] = *(const f32x4*)(z + (size_t)(b * CC + d) * PP + p0 + pt * 16 + lh * 4);
        }

    lds_barrier();

    const int swz = ((lr & 7) << 4) ^ ((lr & 8) << 3);

    for (int i = 1; i <= NSTEP; ++i) {
        const char* xh = (const char*)XH[(i - 1) & 1];
        const char* xl = (const char*)XL[(i - 1) & 1];

        f32x4 acc[2][2];
        #pragma unroll
        for (int pt = 0; pt < 2; ++pt)
            #pragma unroll
            for (int dt = 0; dt < 2; ++dt)
                acc[pt][dt] = (f32x4){0.0f, 0.0f, 0.0f, 0.0f};

        // ---- channel matmul: acc = Xh*Wh + Xl*Wh + Xh*Wl (fp32 accum) ----
        // A-frag (X^T): row p = pt*16 + lr, k = c contiguous -> same LDS reads as before.
        #pragma unroll
        for (int ks = 0; ks < 4; ++ks) {
            const int co = ks * 64 + lh * 16;
            const int r0 = ((lr)      * 256 + co) ^ swz;
            const int r1 = ((16 + lr) * 256 + co) ^ swz;
            bf16x8 a0h = *(const bf16x8*)(xh + r0);
            bf16x8 a1h = *(const bf16x8*)(xh + r1);
            bf16x8 a0l = *(const bf16x8*)(xl + r0);
            bf16x8 a1l = *(const bf16x8*)(xl + r1);
            #pragma unroll
            for (int dt = 0; dt < 2; ++dt) {
                acc[0][dt] = __builtin_amdgcn_mfma_f32_16x16x32_bf16(a0h, wh[dt][ks], acc[0][dt], 0, 0, 0);
                acc[1][dt] = __builtin_amdgcn_mfma_f32_16x16x32_bf16(a1h, wh[dt][ks], acc[1][dt], 0, 0, 0);
                acc[0][dt] = __builtin_amdgcn_mfma_f32_16x16x32_bf16(a0l, wh[dt][ks], acc[0][dt], 0, 0, 0);
                acc[1][dt] = __builtin_amdgcn_mfma_f32_16x16x32_bf16(a1l, wh[dt][ks], acc[1][dt], 0, 0, 0);
                acc[0][dt] = __builtin_amdgcn_mfma_f32_16x16x32_bf16(a0h, wl[dt][ks], acc[0][dt], 0, 0, 0);
                acc[1][dt] = __builtin_amdgcn_mfma_f32_16x16x32_bf16(a1h, wl[dt][ks], acc[1][dt], 0, 0, 0);
            }
        }

        // ---- y = x_old + tanh(acc + bias); state stays in registers ----
        #pragma unroll
        for (int pt = 0; pt < 2; ++pt)
            #pragma unroll
            for (int dt = 0; dt < 2; ++dt)
                #pragma unroll
                for (int j = 0; j < 4; ++j)
                    st[pt][dt][j] += fast_tanh(acc[pt][dt][j] + bv[dt]);

        // ---- publish new bf16 hi/lo state into the WRITE buffer ----
        if (i < NSTEP) {
            char* yh = (char*)XH[i & 1];
            char* yl = (char*)XL[i & 1];
            #pragma unroll
            for (int pt = 0; pt < 2; ++pt)
                #pragma unroll
                for (int dt = 0; dt < 2; ++dt) {
                    const int d = (2 * w + dt) * 16 + lr;
                    #pragma unroll
                    for (int j = 0; j < 4; ++j) {
                        const int p = pt * 16 + lh * 4 + j;
                        unsigned short h, lo;
                        bf16_split(st[pt][dt][j], h, lo);
                        const int off = xb_off(p, d);
                        *(unsigned short*)(yh + off) = h;
                        *(unsigned short*)(yl + off) = lo;
                    }
                }
        }

        // ---- global stores for chunk i (fire-and-forget; never drained at barrier) ----
        const size_t shiftBase = (size_t)i * CHUNK;
        const size_t clsBase   = (size_t)(9 + i) * CHUNK;
        const int s = VV * i;   // flat-position shift (t -> t+i)
        const bool fast = (p0 >= s) && (p0 + PTILE - 1 + s < PP);   // block-uniform
        #pragma unroll
        for (int pt = 0; pt < 2; ++pt) {
            const int P0 = p0 + pt * 16 + lh * 4;
            #pragma unroll
            for (int dt = 0; dt < 2; ++dt) {
                const int d = (2 * w + dt) * 16 + lr;
                const size_t row = (size_t)(b * CC + d) * PP;
                f32x4 y = st[pt][dt];
                *(f32x4*)(out + clsBase + row + P0) = y;          // z_cls chunk i (aligned)
                if (fast) {
                    float* dst = out + shiftBase + row + P0 + s;  // s may be %4 != 0
                    dst[0] = y[0]; dst[1] = y[1]; dst[2] = y[2]; dst[3] = y[3];
                } else {
                    #pragma unroll
                    for (int e = 0; e < 4; ++e) {
                        const int p = P0 + e, q = p + s;
                        if (q < PP) out[shiftBase + row + q] = y[e];
                        if (p < s)  out[shiftBase + row + p] = 0.0f;
                    }
                }
            }
        }

        if (i < NSTEP) lds_barrier();   // LDS-only: publish visible, stores still in flight
    }
}

extern "C" void kernel_launch(void* const* d_in, const int* in_sizes, int n_in,
                              void* d_out, int out_size, void* d_ws, size_t ws_size,
                              hipStream_t stream) {
    const float* z    = (const float*)d_in[0];   // (32,128,64,25) fp32
    const float* W    = (const float*)d_in[1];   // (128,128) fp32
    const float* bias = (const float*)d_in[2];   // (128,) fp32
    float* out = (float*)d_out;                  // 18 * CHUNK fp32
    unsigned short* Wh = (unsigned short*)d_ws;  // 32 KB bf16-hi W
    unsigned short* Wl = Wh + CC * CC;           // 32 KB bf16-lo W

    hipLaunchKernelGGL(wsplit, dim3((CC * CC + 255) / 256), dim3(256), 0, stream, W, Wh, Wl);
    hipLaunchKernelGGL(euler_fused, dim3(NPT, BB), dim3(256), 0, stream, z, Wh, Wl, bias, out);
}